// Round 1
// baseline (4634.021 us; speedup 1.0000x reference)
//
#include <hip/hip_runtime.h>

#define HD 64

__device__ __forceinline__ float relu(float x) { return x > 0.f ? x : 0.f; }

// ---------------- encoders ----------------
__global__ __launch_bounds__(256) void k_node_enc(
    const float* __restrict__ nf, const float* __restrict__ W,
    const float* __restrict__ b, float* __restrict__ h, int N_) {
  int t = blockIdx.x * 256 + threadIdx.x;
  int n = t >> 6, j = t & 63;
  if (n >= N_) return;
  float x0 = nf[(size_t)n * 2 + 0], x1 = nf[(size_t)n * 2 + 1];
  float v = fmaf(x0, W[j], fmaf(x1, W[HD + j], b[j]));
  h[t] = relu(v);
}

__global__ __launch_bounds__(256) void k_edge_enc(
    const float* __restrict__ ea, const float* __restrict__ W,
    const float* __restrict__ b, float* __restrict__ e, long long E_) {
  long long t = (long long)blockIdx.x * 256 + threadIdx.x;
  long long eid = t >> 6;
  int j = (int)(t & 63);
  if (eid >= E_) return;
  const float* row = ea + eid * 4;
  float x0 = row[0], x1 = row[1], x2 = row[2], x3 = row[3];
  float v = b[j];
  v = fmaf(x0, W[0 * HD + j], v);
  v = fmaf(x1, W[1 * HD + j], v);
  v = fmaf(x2, W[2 * HD + j], v);
  v = fmaf(x3, W[3 * HD + j], v);
  e[t] = relu(v);
}

// ---------------- edge MLP: thread-per-edge, 64 accumulators ----------------
// W access is wave-uniform (uniform k, compile-time j) -> scalar loads.
__device__ __forceinline__ void gemv_seg(const float* __restrict__ in,
                                         const float* __restrict__ W,
                                         float acc[HD]) {
#pragma unroll 1
  for (int k = 0; k < HD; k += 4) {
    float4 v = *reinterpret_cast<const float4*>(in + k);
    const float* Wk = W + (size_t)k * HD;
#pragma unroll
    for (int j = 0; j < HD; ++j) {
      float a = acc[j];
      a = fmaf(v.x, Wk[0 * HD + j], a);
      a = fmaf(v.y, Wk[1 * HD + j], a);
      a = fmaf(v.z, Wk[2 * HD + j], a);
      a = fmaf(v.w, Wk[3 * HD + j], a);
      acc[j] = a;
    }
  }
}

__global__ __launch_bounds__(256) void k_edge_mlp(
    const float* __restrict__ h, float* __restrict__ e,
    const int* __restrict__ ei,  // edge_index [2,E]
    const float* __restrict__ W, const float* __restrict__ b, int E_) {
  int eid = blockIdx.x * 256 + threadIdx.x;
  if (eid >= E_) return;
  int s = ei[eid], d = ei[E_ + eid];
  float acc[HD];
#pragma unroll
  for (int j = 0; j < HD; ++j) acc[j] = b[j];
  float* erow = e + (size_t)eid * HD;
  gemv_seg(h + (size_t)s * HD, W, acc);
  gemv_seg(h + (size_t)d * HD, W + HD * HD, acc);
  gemv_seg(erow, W + 2 * HD * HD, acc);
#pragma unroll
  for (int j = 0; j < HD; j += 4) {
    float4 v;
    v.x = relu(acc[j + 0]);
    v.y = relu(acc[j + 1]);
    v.z = relu(acc[j + 2]);
    v.w = relu(acc[j + 3]);
    *reinterpret_cast<float4*>(erow + j) = v;  // m overwrites e in place
  }
}

// ---------------- aggregation: coalesced atomics ----------------
__global__ __launch_bounds__(256) void k_aggr(
    const float* __restrict__ m, const int* __restrict__ dst,
    float* __restrict__ aggr, long long E_) {
  long long t = (long long)blockIdx.x * 256 + threadIdx.x;
  long long eid = t >> 6;
  int j = (int)(t & 63);
  if (eid >= E_) return;
  int d = dst[eid];
  atomicAdd(aggr + (size_t)d * HD + j, m[eid * HD + j]);
}

// ---------------- node MLP (in-place h update) ----------------
__global__ __launch_bounds__(256) void k_node_mlp(
    float* __restrict__ h, const float* __restrict__ aggr,
    const float* __restrict__ W, const float* __restrict__ b, int N_) {
  int t = blockIdx.x * 256 + threadIdx.x;
  int n = t >> 6, j = t & 63;
  if (n >= N_) return;
  const float* hr = h + (size_t)n * HD;
  const float* ar = aggr + (size_t)n * HD;
  float acc = b[j];
#pragma unroll 8
  for (int k = 0; k < HD; ++k) acc = fmaf(hr[k], W[(size_t)k * HD + j], acc);
#pragma unroll 8
  for (int k = 0; k < HD; ++k) acc = fmaf(ar[k], W[(size_t)(HD + k) * HD + j], acc);
  h[t] = relu(acc);
}

// ---------------- decoder / heads ----------------
__global__ __launch_bounds__(256) void k_mat64(
    const float* __restrict__ in, const float* __restrict__ W,
    const float* __restrict__ b, float* __restrict__ out, int N_, int do_relu) {
  int t = blockIdx.x * 256 + threadIdx.x;
  int n = t >> 6, j = t & 63;
  if (n >= N_) return;
  const float* r = in + (size_t)n * HD;
  float acc = b[j];
#pragma unroll 8
  for (int k = 0; k < HD; ++k) acc = fmaf(r[k], W[(size_t)k * HD + j], acc);
  out[t] = do_relu ? relu(acc) : acc;
}

__global__ __launch_bounds__(256) void k_head(
    const float* __restrict__ tbuf, const float* __restrict__ W2,
    const float* __restrict__ b2, float* __restrict__ out, int N_) {
  long long t = (long long)blockIdx.x * 256 + threadIdx.x;
  int n = (int)(t >> 10), g = (int)(t & 1023);
  if (n >= N_) return;
  const float* tr = tbuf + (size_t)n * HD;
  float acc = b2[g];
#pragma unroll 8
  for (int k = 0; k < HD; ++k) acc = fmaf(tr[k], W2[(size_t)k * 1024 + g], acc);
  out[t] = acc;
}

extern "C" void kernel_launch(void* const* d_in, const int* in_sizes, int n_in,
                              void* d_out, int out_size, void* d_ws, size_t ws_size,
                              hipStream_t stream) {
  const float* node_features = (const float*)d_in[0];
  const float* edge_attr     = (const float*)d_in[1];
  const float* node_enc_W    = (const float*)d_in[2];
  const float* node_enc_b    = (const float*)d_in[3];
  const float* edge_enc_W    = (const float*)d_in[4];
  const float* edge_enc_b    = (const float*)d_in[5];
  const float* edge_mlp_W    = (const float*)d_in[6];
  const float* edge_mlp_b    = (const float*)d_in[7];
  const float* node_mlp_W    = (const float*)d_in[8];
  const float* node_mlp_b    = (const float*)d_in[9];
  const float* dec_W         = (const float*)d_in[10];
  const float* dec_b         = (const float*)d_in[11];
  const float* hm1_W         = (const float*)d_in[12];
  const float* hm1_b         = (const float*)d_in[13];
  const float* hm2_W         = (const float*)d_in[14];
  const float* hm2_b         = (const float*)d_in[15];
  const int*   edge_index    = (const int*)d_in[16];

  const int N_ = in_sizes[0] / 2;
  const long long E_ = in_sizes[1] / 4;
  const int R_ = in_sizes[7] / HD;  // edge_mlp_b is [R,H]

  // workspace carve-up (floats): e[E*64] | h[N*64] | aggr[N*64] | t[N*64]
  float* e_buf = (float*)d_ws;
  float* h_buf = e_buf + (size_t)E_ * HD;
  float* aggr  = h_buf + (size_t)N_ * HD;
  float* t_buf = aggr + (size_t)N_ * HD;

  float* out_emb = (float*)d_out;
  float* out_log = out_emb + (size_t)N_ * HD;

  const int nh_blocks = (int)(((size_t)N_ * HD + 255) / 256);
  const int eh_blocks = (int)(((size_t)E_ * HD + 255) / 256);
  const int e_blocks  = (int)((E_ + 255) / 256);

  k_node_enc<<<nh_blocks, 256, 0, stream>>>(node_features, node_enc_W, node_enc_b, h_buf, N_);
  k_edge_enc<<<eh_blocks, 256, 0, stream>>>(edge_attr, edge_enc_W, edge_enc_b, e_buf, E_);

  for (int r = 0; r < R_; ++r) {
    k_edge_mlp<<<e_blocks, 256, 0, stream>>>(
        h_buf, e_buf, edge_index,
        edge_mlp_W + (size_t)r * 3 * HD * HD, edge_mlp_b + (size_t)r * HD, (int)E_);
    hipMemsetAsync(aggr, 0, (size_t)N_ * HD * sizeof(float), stream);
    k_aggr<<<eh_blocks, 256, 0, stream>>>(e_buf, edge_index + E_, aggr, E_);
    k_node_mlp<<<nh_blocks, 256, 0, stream>>>(
        h_buf, aggr, node_mlp_W + (size_t)r * 2 * HD * HD, node_mlp_b + (size_t)r * HD, N_);
  }

  k_mat64<<<nh_blocks, 256, 0, stream>>>(h_buf, dec_W, dec_b, out_emb, N_, 0);
  k_mat64<<<nh_blocks, 256, 0, stream>>>(out_emb, hm1_W, hm1_b, t_buf, N_, 1);
  const int head_blocks = (int)(((size_t)N_ * 1024 + 255) / 256);
  k_head<<<head_blocks, 256, 0, stream>>>(t_buf, hm2_W, hm2_b, out_log, N_);
}

// Round 2
// 1336.286 us; speedup vs baseline: 3.4678x; 3.4678x over previous
//
#include <hip/hip_runtime.h>

#define HD 64

typedef __attribute__((ext_vector_type(8))) short bf16x8;
typedef __attribute__((ext_vector_type(4))) float f32x4;

#define MFMA16(a, b, c) __builtin_amdgcn_mfma_f32_16x16x32_bf16(a, b, c, 0, 0, 0)

__device__ __forceinline__ float relu(float x) { return x > 0.f ? x : 0.f; }

// fp32 -> bf16 round-to-nearest-even
__device__ __forceinline__ unsigned short f2bf(float f) {
  unsigned u = __float_as_uint(f);
  u += 0x7fff + ((u >> 16) & 1);
  return (unsigned short)(u >> 16);
}

__device__ __forceinline__ bf16x8 ldbf8(const unsigned short* p) {
  return *reinterpret_cast<const bf16x8*>(p);
}

// ---------- weight convert + transpose: in [B][K][Nc] f32 -> out [B][Nc][K] bf16 ----------
__global__ __launch_bounds__(256) void k_wt(const float* __restrict__ in,
                                            unsigned short* __restrict__ out,
                                            int K, int Nc) {
  int total = K * Nc;
  int idx = blockIdx.x * 256 + threadIdx.x;
  int batch = blockIdx.y;
  if (idx >= total) return;
  int n = idx / K, k = idx - n * K;
  out[(size_t)batch * total + idx] = f2bf(in[(size_t)batch * total + (size_t)k * Nc + n]);
}

// ---------- encoders (bf16 output state) ----------
__global__ __launch_bounds__(256) void k_node_enc(
    const float* __restrict__ nf, const float* __restrict__ W,
    const float* __restrict__ b, unsigned short* __restrict__ h, int N_) {
  int t = blockIdx.x * 256 + threadIdx.x;
  int n = t >> 6, j = t & 63;
  if (n >= N_) return;
  float x0 = nf[(size_t)n * 2 + 0], x1 = nf[(size_t)n * 2 + 1];
  h[t] = f2bf(relu(fmaf(x0, W[j], fmaf(x1, W[HD + j], b[j]))));
}

__global__ __launch_bounds__(256) void k_edge_enc(
    const float* __restrict__ ea, const float* __restrict__ W,
    const float* __restrict__ b, unsigned short* __restrict__ e, long long E_) {
  long long t = (long long)blockIdx.x * 256 + threadIdx.x;
  long long eid = t >> 6;
  int j = (int)(t & 63);
  if (eid >= E_) return;
  const float* row = ea + eid * 4;
  float v = b[j];
  v = fmaf(row[0], W[0 * HD + j], v);
  v = fmaf(row[1], W[1 * HD + j], v);
  v = fmaf(row[2], W[2 * HD + j], v);
  v = fmaf(row[3], W[3 * HD + j], v);
  e[t] = f2bf(relu(v));
}

// ---------- edge MLP via MFMA + fused scatter-add aggregation ----------
// A = [h[src] | h[dst] | e]  (16 edges x 192) bf16, B = Wt [64][192] bf16.
// Epilogue: relu -> bf16 m written back to e (via LDS transpose, coalesced)
//           and fp32 atomicAdd into aggr[dst].
__global__ __launch_bounds__(256) void k_edge_mfma(
    const unsigned short* __restrict__ h, unsigned short* __restrict__ e,
    const int* __restrict__ ei, const unsigned short* __restrict__ Wt,
    const float* __restrict__ b, float* __restrict__ aggr, int E_) {
  __shared__ unsigned short sm[4][16][64];
  int wid = threadIdx.x >> 6, l = threadIdx.x & 63;
  int tile = blockIdx.x * 4 + wid;  // 16-edge tile, grid sized exactly
  int r0 = tile * 16;
  int lr = l & 15, lk = l >> 4;
  int ea_ = r0 + lr;
  int s = ei[ea_], d = ei[E_ + ea_];
  const unsigned short* hs = h + (size_t)s * HD;
  const unsigned short* hdp = h + (size_t)d * HD;
  const unsigned short* ep = e + (size_t)ea_ * HD;

  f32x4 acc[4] = {};
#pragma unroll
  for (int kk = 0; kk < 6; ++kk) {
    // segment is compile-time after unroll: kk<2 -> h[src], kk<4 -> h[dst], else e
    const unsigned short* base = (kk < 2) ? hs : (kk < 4) ? hdp : ep;
    bf16x8 a = ldbf8(base + (kk & 1) * 32 + lk * 8);
#pragma unroll
    for (int nt = 0; nt < 4; ++nt) {
      bf16x8 bb = ldbf8(Wt + (size_t)(nt * 16 + lr) * 192 + kk * 32 + lk * 8);
      acc[nt] = MFMA16(a, bb, acc[nt]);
    }
  }

  // dst indices for the 4 C rows this lane owns
  int dd0 = ei[E_ + r0 + lk * 4 + 0];
  int dd1 = ei[E_ + r0 + lk * 4 + 1];
  int dd2 = ei[E_ + r0 + lk * 4 + 2];
  int dd3 = ei[E_ + r0 + lk * 4 + 3];
  int dd[4] = {dd0, dd1, dd2, dd3};

#pragma unroll
  for (int nt = 0; nt < 4; ++nt) {
    int col = nt * 16 + lr;
    float bias = b[col];
#pragma unroll
    for (int i = 0; i < 4; ++i) {
      float v = relu(acc[nt][i] + bias);
      sm[wid][lk * 4 + i][col] = f2bf(v);
      atomicAdd(aggr + (size_t)dd[i] * HD + col, v);
    }
  }
  __syncthreads();
  // coalesced bf16 store of m -> e (in place)
  int row = l >> 2, cb = (l & 3) * 16;
  size_t ebase = ((size_t)r0 + row) * HD + cb;
  *reinterpret_cast<bf16x8*>(&e[ebase]) = *reinterpret_cast<const bf16x8*>(&sm[wid][row][cb]);
  *reinterpret_cast<bf16x8*>(&e[ebase + 8]) = *reinterpret_cast<const bf16x8*>(&sm[wid][row][cb + 8]);
}

// ---------- node MLP via MFMA: A = [h | aggr] (16 x 128), in-place h update ----------
__global__ __launch_bounds__(256) void k_node_mfma(
    unsigned short* __restrict__ h, const float* __restrict__ aggr,
    const unsigned short* __restrict__ Wt, const float* __restrict__ b, int ntiles) {
  int wid = threadIdx.x >> 6, l = threadIdx.x & 63;
  int tile = blockIdx.x * 4 + wid;
  if (tile >= ntiles) return;
  int r0 = tile * 16;
  int lr = l & 15, lk = l >> 4;
  int row = r0 + lr;

  f32x4 acc[4] = {};
#pragma unroll
  for (int kk = 0; kk < 4; ++kk) {
    bf16x8 a;
    int off = (kk & 1) * 32 + lk * 8;
    if (kk < 2) {
      a = ldbf8(h + (size_t)row * HD + off);
    } else {
      const float* ap = aggr + (size_t)row * HD + off;
      float4 f0 = *reinterpret_cast<const float4*>(ap);
      float4 f1 = *reinterpret_cast<const float4*>(ap + 4);
      a[0] = f2bf(f0.x); a[1] = f2bf(f0.y); a[2] = f2bf(f0.z); a[3] = f2bf(f0.w);
      a[4] = f2bf(f1.x); a[5] = f2bf(f1.y); a[6] = f2bf(f1.z); a[7] = f2bf(f1.w);
    }
#pragma unroll
    for (int nt = 0; nt < 4; ++nt) {
      bf16x8 bb = ldbf8(Wt + (size_t)(nt * 16 + lr) * 128 + kk * 32 + lk * 8);
      acc[nt] = MFMA16(a, bb, acc[nt]);
    }
  }
#pragma unroll
  for (int nt = 0; nt < 4; ++nt) {
    int col = nt * 16 + lr;
    float bias = b[col];
#pragma unroll
    for (int i = 0; i < 4; ++i) {
      float v = relu(acc[nt][i] + bias);
      h[(size_t)(r0 + lk * 4 + i) * HD + col] = f2bf(v);
    }
  }
}

// ---------- generic 64x64 per-node GEMM (dec / hm1) ----------
__global__ __launch_bounds__(256) void k_gemm64(
    const unsigned short* __restrict__ A, const unsigned short* __restrict__ Wt,
    const float* __restrict__ b, float* __restrict__ outf,
    unsigned short* __restrict__ outb, int do_relu, int ntiles) {
  int wid = threadIdx.x >> 6, l = threadIdx.x & 63;
  int tile = blockIdx.x * 4 + wid;
  if (tile >= ntiles) return;
  int r0 = tile * 16;
  int lr = l & 15, lk = l >> 4;

  f32x4 acc[4] = {};
#pragma unroll
  for (int kk = 0; kk < 2; ++kk) {
    bf16x8 a = ldbf8(A + (size_t)(r0 + lr) * HD + kk * 32 + lk * 8);
#pragma unroll
    for (int nt = 0; nt < 4; ++nt) {
      bf16x8 bb = ldbf8(Wt + (size_t)(nt * 16 + lr) * HD + kk * 32 + lk * 8);
      acc[nt] = MFMA16(a, bb, acc[nt]);
    }
  }
#pragma unroll
  for (int nt = 0; nt < 4; ++nt) {
    int col = nt * 16 + lr;
    float bias = b[col];
#pragma unroll
    for (int i = 0; i < 4; ++i) {
      float v = acc[nt][i] + bias;
      if (do_relu) v = relu(v);
      size_t o = (size_t)(r0 + lk * 4 + i) * HD + col;
      if (outf) outf[o] = v;
      if (outb) outb[o] = f2bf(v);
    }
  }
}

// ---------- heatmap head: [N,64] @ [64,1024] + b, fp32 out via LDS transpose ----------
__global__ __launch_bounds__(256) void k_head_mfma(
    const unsigned short* __restrict__ A, const unsigned short* __restrict__ Wt,
    const float* __restrict__ b2, float* __restrict__ out) {
  __shared__ float sf[4][16][64];
  int wid = threadIdx.x >> 6, l = threadIdx.x & 63;
  int task = blockIdx.x * 4 + wid;  // task = (m-tile, 64-col group)
  int mt = task >> 4, ng = task & 15;
  int r0 = mt * 16, n0 = ng * 64;
  int lr = l & 15, lk = l >> 4;

  f32x4 acc[4] = {};
#pragma unroll
  for (int kk = 0; kk < 2; ++kk) {
    bf16x8 a = ldbf8(A + (size_t)(r0 + lr) * HD + kk * 32 + lk * 8);
#pragma unroll
    for (int nt = 0; nt < 4; ++nt) {
      bf16x8 bb = ldbf8(Wt + (size_t)(n0 + nt * 16 + lr) * HD + kk * 32 + lk * 8);
      acc[nt] = MFMA16(a, bb, acc[nt]);
    }
  }
#pragma unroll
  for (int nt = 0; nt < 4; ++nt) {
    int col = nt * 16 + lr;
    float bias = b2[n0 + col];
#pragma unroll
    for (int i = 0; i < 4; ++i) sf[wid][lk * 4 + i][col] = acc[nt][i] + bias;
  }
  __syncthreads();
  int row = l >> 2, cb = (l & 3) * 16;
  float* op = out + (size_t)(r0 + row) * 1024 + n0 + cb;
#pragma unroll
  for (int q = 0; q < 4; ++q)
    *reinterpret_cast<float4*>(op + q * 4) =
        *reinterpret_cast<const float4*>(&sf[wid][row][cb + q * 4]);
}

extern "C" void kernel_launch(void* const* d_in, const int* in_sizes, int n_in,
                              void* d_out, int out_size, void* d_ws, size_t ws_size,
                              hipStream_t stream) {
  const float* node_features = (const float*)d_in[0];
  const float* edge_attr     = (const float*)d_in[1];
  const float* node_enc_W    = (const float*)d_in[2];
  const float* node_enc_b    = (const float*)d_in[3];
  const float* edge_enc_W    = (const float*)d_in[4];
  const float* edge_enc_b    = (const float*)d_in[5];
  const float* edge_mlp_W    = (const float*)d_in[6];
  const float* edge_mlp_b    = (const float*)d_in[7];
  const float* node_mlp_W    = (const float*)d_in[8];
  const float* node_mlp_b    = (const float*)d_in[9];
  const float* dec_W         = (const float*)d_in[10];
  const float* dec_b         = (const float*)d_in[11];
  const float* hm1_W         = (const float*)d_in[12];
  const float* hm1_b         = (const float*)d_in[13];
  const float* hm2_W         = (const float*)d_in[14];
  const float* hm2_b         = (const float*)d_in[15];
  const int*   edge_index    = (const int*)d_in[16];

  const int N_ = in_sizes[0] / 2;
  const long long E_ = in_sizes[1] / 4;
  const int R_ = in_sizes[7] / HD;

  // workspace carve-up (all chunks 16B-aligned by construction)
  char* p = (char*)d_ws;
  unsigned short* e_bf = (unsigned short*)p; p += (size_t)E_ * HD * 2;
  unsigned short* h_bf = (unsigned short*)p; p += (size_t)N_ * HD * 2;
  float* aggr = (float*)p;                   p += (size_t)N_ * HD * 4;
  unsigned short* emb_bf = (unsigned short*)p; p += (size_t)N_ * HD * 2;
  unsigned short* t_bf = (unsigned short*)p;   p += (size_t)N_ * HD * 2;
  unsigned short* wt_edge = (unsigned short*)p; p += (size_t)R_ * 192 * 64 * 2;
  unsigned short* wt_node = (unsigned short*)p; p += (size_t)R_ * 128 * 64 * 2;
  unsigned short* wt_dec = (unsigned short*)p;  p += 64 * 64 * 2;
  unsigned short* wt_hm1 = (unsigned short*)p;  p += 64 * 64 * 2;
  unsigned short* wt_hm2 = (unsigned short*)p;  p += 1024 * 64 * 2;

  // weight transposes (tiny)
  k_wt<<<dim3((192 * 64 + 255) / 256, R_), 256, 0, stream>>>(edge_mlp_W, wt_edge, 192, 64);
  k_wt<<<dim3((128 * 64 + 255) / 256, R_), 256, 0, stream>>>(node_mlp_W, wt_node, 128, 64);
  k_wt<<<dim3((64 * 64 + 255) / 256, 1), 256, 0, stream>>>(dec_W, wt_dec, 64, 64);
  k_wt<<<dim3((64 * 64 + 255) / 256, 1), 256, 0, stream>>>(hm1_W, wt_hm1, 64, 64);
  k_wt<<<dim3((64 * 1024 + 255) / 256, 1), 256, 0, stream>>>(hm2_W, wt_hm2, 64, 1024);

  const int nh_blocks = (int)(((size_t)N_ * HD + 255) / 256);
  const int eh_blocks = (int)(((size_t)E_ * HD + 255) / 256);
  k_node_enc<<<nh_blocks, 256, 0, stream>>>(node_features, node_enc_W, node_enc_b, h_bf, N_);
  k_edge_enc<<<eh_blocks, 256, 0, stream>>>(edge_attr, edge_enc_W, edge_enc_b, e_bf, E_);

  const int etile_blocks = (int)(E_ / 64);        // E divisible by 64
  const int ntiles = (N_ + 15) / 16;
  const int nblocks = (ntiles + 3) / 4;
  for (int r = 0; r < R_; ++r) {
    hipMemsetAsync(aggr, 0, (size_t)N_ * HD * 4, stream);
    k_edge_mfma<<<etile_blocks, 256, 0, stream>>>(
        h_bf, e_bf, edge_index, wt_edge + (size_t)r * 192 * 64,
        edge_mlp_b + (size_t)r * HD, aggr, (int)E_);
    k_node_mfma<<<nblocks, 256, 0, stream>>>(
        h_bf, aggr, wt_node + (size_t)r * 128 * 64, node_mlp_b + (size_t)r * HD, ntiles);
  }

  float* out_emb = (float*)d_out;
  float* out_log = out_emb + (size_t)N_ * HD;
  k_gemm64<<<nblocks, 256, 0, stream>>>(h_bf, wt_dec, dec_b, out_emb, emb_bf, 0, ntiles);
  k_gemm64<<<nblocks, 256, 0, stream>>>(emb_bf, wt_hm1, hm1_b, nullptr, t_bf, 1, ntiles);
  k_head_mfma<<<ntiles * 4, 256, 0, stream>>>(t_bf, wt_hm2, hm2_b, out_log);
}